// Round 1
// baseline (417.168 us; speedup 1.0000x reference)
//
#include <hip/hip_runtime.h>
#include <hip/hip_bf16.h>
#include <stdint.h>
#include <type_traits>

// ---------------------------------------------------------------------------
// MultiExpertMoELayer: opcode-routed 2-stage FFN chain.
//   op = argmax(x[0,0,0:8]);  for e in 0..1: x = gelu(x@W1[op,e]+b1)@W2[op,e]+b2
// Strategy: on-device routing -> bf16 convert/transpose of selected weights ->
// 4x (128x128-tile bf16 MFMA GEMM, m97 structure, global_load_lds + XOR swizzle)
// ---------------------------------------------------------------------------

typedef __attribute__((ext_vector_type(8))) short short8;   // 8 x bf16 (4 VGPR)
typedef __attribute__((ext_vector_type(4))) float f32x4;    // MFMA accum

__device__ __forceinline__ unsigned short f2bf(float f) {
  union { float f; uint32_t u; } v; v.f = f;
  return (unsigned short)((v.u + 0x7fffu + ((v.u >> 16) & 1u)) >> 16);  // RNE
}

// jax.nn.gelu(approximate=True): 0.5x(1+tanh(sqrt(2/pi)(x+0.044715x^3)))
__device__ __forceinline__ float gelu_tanh(float x) {
  float u = 0.7978845608028654f * (x + 0.044715f * x * x * x);
  float e = __expf(2.0f * u);
  float t = 1.0f - 2.0f / (e + 1.0f);   // tanh(u), safe at +/-inf
  return 0.5f * x * (1.0f + t);
}

__device__ __forceinline__ void gload_lds16(const void* g, void* l) {
  __builtin_amdgcn_global_load_lds(
      (const __attribute__((address_space(1))) void*)g,
      (__attribute__((address_space(3))) void*)l, 16, 0, 0);
}

// --------------------------- routing ---------------------------------------
__global__ void route_kernel(const float* __restrict__ x, int* __restrict__ op_out) {
  if (threadIdx.x == 0) {
    int best = 0; float bv = x[0];
    for (int i = 1; i < 8; ++i) { float v = x[i]; if (v > bv) { bv = v; best = i; } }
    *op_out = best;   // first-max wins, matches jnp.argmax
  }
}

// --------------------------- converts --------------------------------------
__global__ void cvt_x_kernel(const float* __restrict__ x, unsigned short* __restrict__ xb, int n4) {
  int i = blockIdx.x * blockDim.x + threadIdx.x;
  if (i >= n4) return;
  float4 v = ((const float4*)x)[i];
  ushort4 o; o.x = f2bf(v.x); o.y = f2bf(v.y); o.z = f2bf(v.z); o.w = f2bf(v.w);
  ((ushort4*)xb)[i] = o;
}

// in: fp32 [R][C] (opcode/expert-selected at runtime) -> out: bf16 [C][R]
__global__ void transpose_cvt_kernel(const float* __restrict__ Wbase,
                                     unsigned short* __restrict__ outb,
                                     const int* __restrict__ op_ptr,
                                     int R, int C, int expert) {
  __shared__ float tile[64][65];
  const int op = *op_ptr;
  const float* W = Wbase + ((size_t)op * 2 + (size_t)expert) * (size_t)R * (size_t)C;
  const int tr = blockIdx.y, tc = blockIdx.x;
  const int t = threadIdx.x;
  {
    const int r  = t >> 2;
    const int c0 = (t & 3) * 16;
    const float* src = W + (size_t)(tr * 64 + r) * C + tc * 64 + c0;
#pragma unroll
    for (int j = 0; j < 16; j += 4) {
      float4 v = *(const float4*)(src + j);
      tile[r][c0 + j]     = v.x;
      tile[r][c0 + j + 1] = v.y;
      tile[r][c0 + j + 2] = v.z;
      tile[r][c0 + j + 3] = v.w;
    }
  }
  __syncthreads();
  {
    const int c  = t >> 2;
    const int r0 = (t & 3) * 16;
    unsigned short* dst = outb + (size_t)(tc * 64 + c) * R + tr * 64 + r0;
#pragma unroll
    for (int j = 0; j < 16; j += 4) {
      ushort4 o;
      o.x = f2bf(tile[r0 + j][c]);
      o.y = f2bf(tile[r0 + j + 1][c]);
      o.z = f2bf(tile[r0 + j + 2][c]);
      o.w = f2bf(tile[r0 + j + 3][c]);
      *(ushort4*)(dst + j) = o;
    }
  }
}

// --------------------------- GEMM (C = A @ Bt^T + bias [,gelu]) ------------
// A: [M][K] bf16, Bt: [N][K] bf16 (both K-major -> symmetric frag loads).
// 128x128 tile, BK=64, 4 waves (2x2), 4x4 frags of 16x16x32 per wave.
// Staging: global_load_lds 16B, linear LDS dest, source pre-swizzled with
// chunk ^= (row&7); reads apply the same XOR (guideline-21 both-sides).
template<typename OUT_T, bool GELU>
__global__ __launch_bounds__(256) void gemm_bt(
    const unsigned short* __restrict__ A,
    const unsigned short* __restrict__ Bt,
    const float* __restrict__ bias_base,     // [8][2][N]
    const int* __restrict__ op_ptr, int expert,
    OUT_T* __restrict__ Cout, int M, int N, int K)
{
  constexpr int BM = 128, BN = 128, BK = 64;
  __shared__ short smem[2 * BM * BK];
  short* sA = smem;
  short* sB = smem + BM * BK;

  const int tid  = threadIdx.x;
  const int wave = tid >> 6;
  const int lane = tid & 63;
  const int wr = wave >> 1, wc = wave & 1;       // wave grid 2x2 of 64x64
  const int lq = lane >> 4, lr = lane & 15;
  const int bm = blockIdx.y, bn = blockIdx.x;

  const unsigned short* Ab = A  + (size_t)bm * BM * K;
  const unsigned short* Bb = Bt + (size_t)bn * BN * K;

  f32x4 acc[4][4] = {};

  const int nkt = K / BK;
  for (int kt = 0; kt < nkt; ++kt) {
    const int kbase = kt * BK;
#pragma unroll
    for (int i = 0; i < 4; ++i) {
      int ci  = i * 256 + tid;                 // linear 16B-chunk idx, 0..1023
      int row = ci >> 3;                       // tile row (stride 8 chunks)
      int gc  = (ci & 7) ^ (row & 7);          // inverse-swizzled source chunk
      gload_lds16(Ab + (size_t)row * K + kbase + gc * 8, sA + ci * 8);
      gload_lds16(Bb + (size_t)row * K + kbase + gc * 8, sB + ci * 8);
    }
    __syncthreads();                           // drains vmcnt before compute
#pragma unroll
    for (int ks = 0; ks < 2; ++ks) {
      short8 af[4], bfr[4];
#pragma unroll
      for (int m = 0; m < 4; ++m) {
        int ra = wr * 64 + m * 16 + lr;        // A row (lane&15 = MFMA row)
        int ch = ((ks << 2) | lq) ^ (ra & 7);  // swizzled k-chunk
        af[m] = *(const short8*)((const char*)sA + ra * 128 + ch * 16);
      }
#pragma unroll
      for (int n = 0; n < 4; ++n) {
        int rb = wc * 64 + n * 16 + lr;        // B col (lane&15 = MFMA col)
        int ch = ((ks << 2) | lq) ^ (rb & 7);
        bfr[n] = *(const short8*)((const char*)sB + rb * 128 + ch * 16);
      }
#pragma unroll
      for (int m = 0; m < 4; ++m)
#pragma unroll
        for (int n = 0; n < 4; ++n)
          acc[m][n] = __builtin_amdgcn_mfma_f32_16x16x32_bf16(af[m], bfr[n], acc[m][n], 0, 0, 0);
    }
    __syncthreads();
  }

  // Epilogue: C/D layout col=lane&15, row=(lane>>4)*4+reg [m89-verified]
  const int op = *op_ptr;
  const float* bias = bias_base + ((size_t)op * 2 + (size_t)expert) * (size_t)N;
#pragma unroll
  for (int m = 0; m < 4; ++m) {
    const int grow0 = bm * BM + wr * 64 + m * 16 + lq * 4;
#pragma unroll
    for (int n = 0; n < 4; ++n) {
      const int gcol = bn * BN + wc * 64 + n * 16 + lr;
      const float bv = bias[gcol];
#pragma unroll
      for (int r = 0; r < 4; ++r) {
        float v = acc[m][n][r] + bv;
        if constexpr (GELU) v = gelu_tanh(v);
        const size_t off = (size_t)(grow0 + r) * N + gcol;
        if constexpr (std::is_same<OUT_T, float>::value) Cout[off] = v;
        else Cout[off] = f2bf(v);
      }
    }
  }
}

// --------------------------- launcher ---------------------------------------
extern "C" void kernel_launch(void* const* d_in, const int* in_sizes, int n_in,
                              void* d_out, int out_size, void* d_ws, size_t ws_size,
                              hipStream_t stream) {
  const float* x  = (const float*)d_in[0];
  const float* W1 = (const float*)d_in[1];   // [8][2][1024][4096]
  const float* b1 = (const float*)d_in[2];   // [8][2][4096]
  const float* W2 = (const float*)d_in[3];   // [8][2][4096][1024]
  const float* b2 = (const float*)d_in[4];   // [8][2][1024]
  float* out = (float*)d_out;

  const int D = 1024, F = 4096, M = 8192;    // M = B*S = 4*2048

  // ws layout: [op int, pad 1KB][xb 16.8MB][w1t 16.8MB][w2t 16.8MB][h 67.1MB]
  char* ws = (char*)d_ws;
  int* op_ptr = (int*)ws;
  unsigned short* xb  = (unsigned short*)(ws + 1024);
  unsigned short* w1t = (unsigned short*)(ws + 1024 + (size_t)M * D * 2);
  unsigned short* w2t = (unsigned short*)(ws + 1024 + (size_t)M * D * 2 + (size_t)2 * D * F * 2);
  unsigned short* h   = (unsigned short*)(ws + 1024 + (size_t)M * D * 2 + (size_t)4 * D * F * 2);
  unsigned short* x1b = (unsigned short*)d_out;  // stage-0 output parked in d_out (safe: fully overwritten by final GEMM after x1b's last read)

  route_kernel<<<1, 64, 0, stream>>>(x, op_ptr);
  cvt_x_kernel<<<(M * D / 4 + 255) / 256, 256, 0, stream>>>(x, xb, M * D / 4);

  for (int e = 0; e < 2; ++e) {
    // W1[op,e]: [D][F] -> w1t[e]: [F][D]
    transpose_cvt_kernel<<<dim3(F / 64, D / 64), 256, 0, stream>>>(W1, w1t + (size_t)e * F * D, op_ptr, D, F, e);
    // W2[op,e]: [F][D] -> w2t[e]: [D][F]
    transpose_cvt_kernel<<<dim3(D / 64, F / 64), 256, 0, stream>>>(W2, w2t + (size_t)e * D * F, op_ptr, F, D, e);
  }

  // expert 0
  gemm_bt<unsigned short, true ><<<dim3(F / 128, M / 128), 256, 0, stream>>>(xb,  w1t,                 b1, op_ptr, 0, h,   M, F, D);
  gemm_bt<unsigned short, false><<<dim3(D / 128, M / 128), 256, 0, stream>>>(h,   w2t,                 b2, op_ptr, 0, x1b, M, D, F);
  // expert 1
  gemm_bt<unsigned short, true ><<<dim3(F / 128, M / 128), 256, 0, stream>>>(x1b, w1t + (size_t)F * D, b1, op_ptr, 1, h,   M, F, D);
  gemm_bt<float,          false><<<dim3(D / 128, M / 128), 256, 0, stream>>>(h,   w2t + (size_t)D * F, b2, op_ptr, 1, out, M, D, F);
}

// Round 2
// 381.179 us; speedup vs baseline: 1.0944x; 1.0944x over previous
//
#include <hip/hip_runtime.h>
#include <hip/hip_bf16.h>
#include <stdint.h>
#include <type_traits>

// ---------------------------------------------------------------------------
// MultiExpertMoELayer: opcode-routed 2-stage FFN chain.
//   op = argmax(x[0,0,0:8]);  for e in 0..1: x = gelu(x@W1[op,e]+b1)@W2[op,e]+b2
// Round 1: 256-row-tile counted-vmcnt pipelined GEMM (T2+T3+T4+T5):
//   - BM=256, BK=64, 8 waves (2x4), double-buffered LDS, prefetch depth 1 tile
//   - s_waitcnt vmcnt(L) never drains to 0 in steady state (T4)
//   - chunk-XOR LDS swizzle, both-sides (same scheme as round 0, verified)
//   - s_setprio(1) around MFMA clusters (T5)
// GEMM1 uses BN=256 (grid 512 wg); GEMM2 uses BN=128 (grid 256 wg = 1/CU).
// ---------------------------------------------------------------------------

typedef __attribute__((ext_vector_type(8))) short short8;   // 8 x bf16 (4 VGPR)
typedef __attribute__((ext_vector_type(4))) float f32x4;    // MFMA accum

__device__ __forceinline__ unsigned short f2bf(float f) {
  union { float f; uint32_t u; } v; v.f = f;
  return (unsigned short)((v.u + 0x7fffu + ((v.u >> 16) & 1u)) >> 16);  // RNE
}

// jax.nn.gelu(approximate=True): 0.5x(1+tanh(sqrt(2/pi)(x+0.044715x^3)))
__device__ __forceinline__ float gelu_tanh(float x) {
  float u = 0.7978845608028654f * (x + 0.044715f * x * x * x);
  float e = __expf(2.0f * u);
  float t = 1.0f - 2.0f / (e + 1.0f);   // tanh(u), safe at +/-inf
  return 0.5f * x * (1.0f + t);
}

__device__ __forceinline__ void gload_lds16(const void* g, void* l) {
  __builtin_amdgcn_global_load_lds(
      (const __attribute__((address_space(1))) void*)g,
      (__attribute__((address_space(3))) void*)l, 16, 0, 0);
}

// --------------------------- routing ---------------------------------------
__global__ void route_kernel(const float* __restrict__ x, int* __restrict__ op_out) {
  if (threadIdx.x == 0) {
    int best = 0; float bv = x[0];
    for (int i = 1; i < 8; ++i) { float v = x[i]; if (v > bv) { bv = v; best = i; } }
    *op_out = best;   // first-max wins, matches jnp.argmax
  }
}

// --------------------------- converts --------------------------------------
__global__ void cvt_x_kernel(const float* __restrict__ x, unsigned short* __restrict__ xb, int n4) {
  int i = blockIdx.x * blockDim.x + threadIdx.x;
  if (i >= n4) return;
  float4 v = ((const float4*)x)[i];
  ushort4 o; o.x = f2bf(v.x); o.y = f2bf(v.y); o.z = f2bf(v.z); o.w = f2bf(v.w);
  ((ushort4*)xb)[i] = o;
}

// in: fp32 [R][C] (opcode/expert-selected at runtime) -> out: bf16 [C][R]
__global__ void transpose_cvt_kernel(const float* __restrict__ Wbase,
                                     unsigned short* __restrict__ outb,
                                     const int* __restrict__ op_ptr,
                                     int R, int C, int expert) {
  __shared__ float tile[64][65];
  const int op = *op_ptr;
  const float* W = Wbase + ((size_t)op * 2 + (size_t)expert) * (size_t)R * (size_t)C;
  const int tr = blockIdx.y, tc = blockIdx.x;
  const int t = threadIdx.x;
  {
    const int r  = t >> 2;
    const int c0 = (t & 3) * 16;
    const float* src = W + (size_t)(tr * 64 + r) * C + tc * 64 + c0;
#pragma unroll
    for (int j = 0; j < 16; j += 4) {
      float4 v = *(const float4*)(src + j);
      tile[r][c0 + j]     = v.x;
      tile[r][c0 + j + 1] = v.y;
      tile[r][c0 + j + 2] = v.z;
      tile[r][c0 + j + 3] = v.w;
    }
  }
  __syncthreads();
  {
    const int c  = t >> 2;
    const int r0 = (t & 3) * 16;
    unsigned short* dst = outb + (size_t)(tc * 64 + c) * R + tr * 64 + r0;
#pragma unroll
    for (int j = 0; j < 16; j += 4) {
      ushort4 o;
      o.x = f2bf(tile[r0 + j][c]);
      o.y = f2bf(tile[r0 + j + 1][c]);
      o.z = f2bf(tile[r0 + j + 2][c]);
      o.w = f2bf(tile[r0 + j + 3][c]);
      *(ushort4*)(dst + j) = o;
    }
  }
}

// --------------------------- pipelined GEMM ---------------------------------
// C = A @ Bt^T + bias [,gelu].  A: [M][K] bf16, Bt: [N][K] bf16.
// BM=256, BN=FN*64, BK=64. 8 waves (2 M x 4 N), per-wave 128 x FN*16.

template<int NINSTR>
__device__ __forceinline__ void stage_tile(const unsigned short* __restrict__ G,
                                           int K, int kbase, short* lds, int tid) {
#pragma unroll
  for (int i = 0; i < NINSTR; ++i) {
    int ci  = i * 512 + tid;              // 16B-chunk index within tile
    int row = ci >> 3;                    // tile row (8 chunks per 64-col row)
    int gc  = (ci & 7) ^ (row & 7);       // inverse-swizzled source chunk
    gload_lds16(G + (size_t)row * K + kbase + gc * 8, lds + ci * 8);
  }
}

template<int VM> __device__ __forceinline__ void wait_vm() {
  if constexpr (VM == 8)      asm volatile("s_waitcnt vmcnt(8)" ::: "memory");
  else if constexpr (VM == 6) asm volatile("s_waitcnt vmcnt(6)" ::: "memory");
  else                        asm volatile("s_waitcnt vmcnt(0)" ::: "memory");
}

template<int FN, bool GELU, typename OUT_T>
__global__ __launch_bounds__(512, 2) void gemm_pipe(
    const unsigned short* __restrict__ A,
    const unsigned short* __restrict__ Bt,
    const float* __restrict__ bias_base,     // [8][2][N]
    const int* __restrict__ op_ptr, int expert,
    OUT_T* __restrict__ Cout, int M, int N, int K, int nbm)
{
  constexpr int BM = 256, BK = 64;
  constexpr int BN = FN * 64;
  constexpr int WN = FN * 16;
  constexpr int LA = 4;                 // A stage instrs/tile (256*64*2B / 512thr / 16B)
  constexpr int LB = FN;                // B stage instrs/tile
  constexpr int L  = LA + LB;           // in-flight loads at the counted wait
  constexpr int BUF = BM * BK + BN * BK;  // shorts per double-buffer half
  __shared__ short smem[2 * BUF];

  const int tid  = threadIdx.x;
  const int wid  = tid >> 6, lane = tid & 63;
  const int wm   = wid >> 2, wn = wid & 3;       // wave grid 2 x 4
  const int lq   = lane >> 4, lr = lane & 15;

  // XCD-aware bijective swizzle (nwg % 8 == 0 for all our launches)
  const int nwg = gridDim.x;
  const int id  = blockIdx.x;
  const int s   = (id & 7) * (nwg >> 3) + (id >> 3);
  const int bn  = s / nbm, bm = s % nbm;

  const unsigned short* Ab = A  + (size_t)bm * BM * K;
  const unsigned short* Bb = Bt + (size_t)bn * BN * K;

  f32x4 acc[8][FN] = {};

  // prologue: stage tile 0 into buffer 0
  stage_tile<LA>(Ab, K, 0, smem, tid);
  stage_tile<LB>(Bb, K, 0, smem + BM * BK, tid);

  const int nkt = K / BK;
  for (int t = 0; t < nkt; ++t) {
    short* cbuf = smem + (t & 1) * BUF;
    if (t + 1 < nkt) {
      short* nbuf = smem + ((t + 1) & 1) * BUF;
      stage_tile<LA>(Ab, K, (t + 1) * BK, nbuf, tid);
      stage_tile<LB>(Bb, K, (t + 1) * BK, nbuf + BM * BK, tid);
      wait_vm<L>();                     // tile t landed; t+1 stays in flight (T4)
    } else {
      wait_vm<0>();
    }
    __builtin_amdgcn_s_barrier();
    __builtin_amdgcn_sched_barrier(0);

    const char* cA = (const char*)cbuf;
    const char* cB = (const char*)(cbuf + BM * BK);
#pragma unroll
    for (int qm = 0; qm < 2; ++qm) {
      short8 af[4][2];
#pragma unroll
      for (int mm = 0; mm < 4; ++mm) {
        int ra = wm * 128 + qm * 64 + mm * 16 + lr;
#pragma unroll
        for (int ks = 0; ks < 2; ++ks) {
          int ch = (ks * 4 + lq) ^ (ra & 7);
          af[mm][ks] = *(const short8*)(cA + ra * 128 + ch * 16);
        }
      }
#pragma unroll
      for (int qn = 0; qn < 2; ++qn) {
        short8 bfr[FN / 2][2];
#pragma unroll
        for (int nn = 0; nn < FN / 2; ++nn) {
          int rb = wn * WN + (qn * (FN / 2) + nn) * 16 + lr;
#pragma unroll
          for (int ks = 0; ks < 2; ++ks) {
            int ch = (ks * 4 + lq) ^ (rb & 7);
            bfr[nn][ks] = *(const short8*)(cB + rb * 128 + ch * 16);
          }
        }
        __builtin_amdgcn_s_setprio(1);
#pragma unroll
        for (int mm = 0; mm < 4; ++mm)
#pragma unroll
          for (int nn = 0; nn < FN / 2; ++nn)
#pragma unroll
            for (int ks = 0; ks < 2; ++ks)
              acc[qm * 4 + mm][qn * (FN / 2) + nn] =
                  __builtin_amdgcn_mfma_f32_16x16x32_bf16(
                      af[mm][ks], bfr[nn][ks],
                      acc[qm * 4 + mm][qn * (FN / 2) + nn], 0, 0, 0);
        __builtin_amdgcn_s_setprio(0);
      }
    }
    asm volatile("s_waitcnt lgkmcnt(0)" ::: "memory");  // all reads of cbuf done
    __builtin_amdgcn_sched_barrier(0);
    __builtin_amdgcn_s_barrier();       // now t+2's stages may overwrite cbuf
  }

  // Epilogue: C/D layout col=lane&15, row=(lane>>4)*4+reg [m89-verified]
  const int op = *op_ptr;
  const float* bias = bias_base + ((size_t)op * 2 + (size_t)expert) * (size_t)N;
#pragma unroll
  for (int f = 0; f < 8; ++f) {
    const int grow0 = bm * BM + wm * 128 + f * 16 + lq * 4;
#pragma unroll
    for (int n = 0; n < FN; ++n) {
      const int gcol = bn * BN + wn * WN + n * 16 + lr;
      const float bv = bias[gcol];
#pragma unroll
      for (int r = 0; r < 4; ++r) {
        float v = acc[f][n][r] + bv;
        if constexpr (GELU) v = gelu_tanh(v);
        const size_t off = (size_t)(grow0 + r) * N + gcol;
        if constexpr (std::is_same<OUT_T, float>::value) Cout[off] = v;
        else Cout[off] = f2bf(v);
      }
    }
  }
}

// --------------------------- launcher ---------------------------------------
extern "C" void kernel_launch(void* const* d_in, const int* in_sizes, int n_in,
                              void* d_out, int out_size, void* d_ws, size_t ws_size,
                              hipStream_t stream) {
  const float* x  = (const float*)d_in[0];
  const float* W1 = (const float*)d_in[1];   // [8][2][1024][4096]
  const float* b1 = (const float*)d_in[2];   // [8][2][4096]
  const float* W2 = (const float*)d_in[3];   // [8][2][4096][1024]
  const float* b2 = (const float*)d_in[4];   // [8][2][1024]
  float* out = (float*)d_out;

  const int D = 1024, F = 4096, M = 8192;    // M = B*S = 4*2048

  // ws layout: [op int, pad 1KB][xb 16.8MB][w1t 16.8MB][w2t 16.8MB][h 67.1MB]
  char* ws = (char*)d_ws;
  int* op_ptr = (int*)ws;
  unsigned short* xb  = (unsigned short*)(ws + 1024);
  unsigned short* w1t = (unsigned short*)(ws + 1024 + (size_t)M * D * 2);
  unsigned short* w2t = (unsigned short*)(ws + 1024 + (size_t)M * D * 2 + (size_t)2 * D * F * 2);
  unsigned short* h   = (unsigned short*)(ws + 1024 + (size_t)M * D * 2 + (size_t)4 * D * F * 2);
  unsigned short* x1b = (unsigned short*)d_out;  // stage-0 output parked in d_out

  route_kernel<<<1, 64, 0, stream>>>(x, op_ptr);
  cvt_x_kernel<<<(M * D / 4 + 255) / 256, 256, 0, stream>>>(x, xb, M * D / 4);

  for (int e = 0; e < 2; ++e) {
    // W1[op,e]: [D][F] -> w1t[e]: [F][D]
    transpose_cvt_kernel<<<dim3(F / 64, D / 64), 256, 0, stream>>>(W1, w1t + (size_t)e * F * D, op_ptr, D, F, e);
    // W2[op,e]: [F][D] -> w2t[e]: [D][F]
    transpose_cvt_kernel<<<dim3(D / 64, F / 64), 256, 0, stream>>>(W2, w2t + (size_t)e * D * F, op_ptr, F, D, e);
  }

  // GEMM1: M=8192, N=4096, K=1024 -> BN=256, grid 32*16=512
  // GEMM2: M=8192, N=1024, K=4096 -> BN=128, grid 32*8 =256
  const int nbm = M / 256;
  // expert 0
  gemm_pipe<4, true,  unsigned short><<<(M/256)*(F/256), 512, 0, stream>>>(xb,  w1t,                 b1, op_ptr, 0, h,   M, F, D, nbm);
  gemm_pipe<2, false, unsigned short><<<(M/256)*(D/128), 512, 0, stream>>>(h,   w2t,                 b2, op_ptr, 0, x1b, M, D, F, nbm);
  // expert 1
  gemm_pipe<4, true,  unsigned short><<<(M/256)*(F/256), 512, 0, stream>>>(x1b, w1t + (size_t)F * D, b1, op_ptr, 1, h,   M, F, D, nbm);
  gemm_pipe<2, false, float         ><<<(M/256)*(D/128), 512, 0, stream>>>(h,   w2t + (size_t)D * F, b2, op_ptr, 1, out, M, D, F, nbm);
}

// Round 3
// 359.457 us; speedup vs baseline: 1.1606x; 1.0604x over previous
//
#include <hip/hip_runtime.h>
#include <hip/hip_bf16.h>
#include <stdint.h>
#include <type_traits>

// ---------------------------------------------------------------------------
// MultiExpertMoELayer: opcode-routed 2-stage FFN chain.
//   op = argmax(x[0,0,0:8]);  for e in 0..1: x = gelu(x@W1[op,e]+b1)@W2[op,e]+b2
// Round 2: true phase-split pipelined GEMM (T2+T3+T4+T5, m201-style):
//   - BM=256, BK=64, 8 waves (2M x 4N), double-buffered LDS
//   - 4 phases per K-tile (ks-half x M-half), 16 MFMA per phase behind
//     {ds_read cluster -> stage-issue -> lgkmcnt(0) -> setprio(1) MFMA}
//   - counted s_waitcnt vmcnt(2) at tile boundary; never drained mid-loop
//   - staging always targets the idle buffer half (race-free by construction)
//   - chunk-XOR LDS swizzle identical to round 0/1 (verified numerics)
// ---------------------------------------------------------------------------

typedef __attribute__((ext_vector_type(8))) short short8;   // 8 x bf16 (4 VGPR)
typedef __attribute__((ext_vector_type(4))) float f32x4;    // MFMA accum

#define VMCNT2 asm volatile("s_waitcnt vmcnt(2)" ::: "memory")
#define VMCNT0 asm volatile("s_waitcnt vmcnt(0)" ::: "memory")
#define LGKM0  asm volatile("s_waitcnt lgkmcnt(0)" ::: "memory")
#define SBAR   __builtin_amdgcn_s_barrier()
#define SCHEDB __builtin_amdgcn_sched_barrier(0)

__device__ __forceinline__ unsigned short f2bf(float f) {
  union { float f; uint32_t u; } v; v.f = f;
  return (unsigned short)((v.u + 0x7fffu + ((v.u >> 16) & 1u)) >> 16);  // RNE
}

// jax.nn.gelu(approximate=True): 0.5x(1+tanh(sqrt(2/pi)(x+0.044715x^3)))
__device__ __forceinline__ float gelu_tanh(float x) {
  float u = 0.7978845608028654f * (x + 0.044715f * x * x * x);
  float e = __expf(2.0f * u);
  float t = 1.0f - 2.0f / (e + 1.0f);   // tanh(u), safe at +/-inf
  return 0.5f * x * (1.0f + t);
}

__device__ __forceinline__ void gload_lds16(const void* g, void* l) {
  __builtin_amdgcn_global_load_lds(
      (const __attribute__((address_space(1))) void*)g,
      (__attribute__((address_space(3))) void*)l, 16, 0, 0);
}

// --------------------------- routing ---------------------------------------
__global__ void route_kernel(const float* __restrict__ x, int* __restrict__ op_out) {
  if (threadIdx.x == 0) {
    int best = 0; float bv = x[0];
    for (int i = 1; i < 8; ++i) { float v = x[i]; if (v > bv) { bv = v; best = i; } }
    *op_out = best;   // first-max wins, matches jnp.argmax
  }
}

// --------------------------- converts --------------------------------------
__global__ void cvt_x_kernel(const float* __restrict__ x, unsigned short* __restrict__ xb, int n4) {
  int i = blockIdx.x * blockDim.x + threadIdx.x;
  if (i >= n4) return;
  float4 v = ((const float4*)x)[i];
  ushort4 o; o.x = f2bf(v.x); o.y = f2bf(v.y); o.z = f2bf(v.z); o.w = f2bf(v.w);
  ((ushort4*)xb)[i] = o;
}

// in: fp32 [R][C] (opcode/expert-selected at runtime) -> out: bf16 [C][R]
__global__ void transpose_cvt_kernel(const float* __restrict__ Wbase,
                                     unsigned short* __restrict__ outb,
                                     const int* __restrict__ op_ptr,
                                     int R, int C, int expert) {
  __shared__ float tile[64][65];
  const int op = *op_ptr;
  const float* W = Wbase + ((size_t)op * 2 + (size_t)expert) * (size_t)R * (size_t)C;
  const int tr = blockIdx.y, tc = blockIdx.x;
  const int t = threadIdx.x;
  {
    const int r  = t >> 2;
    const int c0 = (t & 3) * 16;
    const float* src = W + (size_t)(tr * 64 + r) * C + tc * 64 + c0;
#pragma unroll
    for (int j = 0; j < 16; j += 4) {
      float4 v = *(const float4*)(src + j);
      tile[r][c0 + j]     = v.x;
      tile[r][c0 + j + 1] = v.y;
      tile[r][c0 + j + 2] = v.z;
      tile[r][c0 + j + 3] = v.w;
    }
  }
  __syncthreads();
  {
    const int c  = t >> 2;
    const int r0 = (t & 3) * 16;
    unsigned short* dst = outb + (size_t)(tc * 64 + c) * R + tr * 64 + r0;
#pragma unroll
    for (int j = 0; j < 16; j += 4) {
      ushort4 o;
      o.x = f2bf(tile[r0 + j][c]);
      o.y = f2bf(tile[r0 + j + 1][c]);
      o.z = f2bf(tile[r0 + j + 2][c]);
      o.w = f2bf(tile[r0 + j + 3][c]);
      *(ushort4*)(dst + j) = o;
    }
  }
}

// --------------------------- phase-split GEMM -------------------------------
// C = A @ Bt^T + bias [,gelu].  A: [M][K] bf16, Bt: [N][K] bf16.
// BM=256, BN=FN*64, BK=64. 8 waves (2M x 4N), per-wave 128 x FN*16.
// LDS per buffer: A 256x64 + B (FN*64)x64 bf16, row-major 64-k rows,
// 16B chunk c stored at c ^ (row&7) (both-sides swizzle w/ staging source).

template<int FN>
__device__ __forceinline__ void stage_pair(
    int j0, const unsigned short* __restrict__ Ab,
    const unsigned short* __restrict__ Bb,
    int K, int kb, short* __restrict__ nxt, int tid) {
  constexpr int ABK = 256 * 64;   // shorts in A region
#pragma unroll
  for (int d = 0; d < 2; ++d) {
    const int j = j0 + d;
    if (j < 4) {                   // A stream: 4 instrs cover 256x64
      const int ci = j * 512 + tid;
      const int row = ci >> 3;
      const int gc = (ci & 7) ^ (row & 7);
      gload_lds16(Ab + (size_t)row * K + kb + gc * 8, nxt + ci * 8);
    } else {                       // B stream: FN instrs cover (FN*64)x64
      const int cj = (j - 4) * 512 + tid;
      const int row = cj >> 3;
      const int gc = (cj & 7) ^ (row & 7);
      gload_lds16(Bb + (size_t)row * K + kb + gc * 8, nxt + ABK + cj * 8);
    }
  }
}

template<int FN, bool GELU, typename OUT_T>
__global__ __launch_bounds__(512, 2) void gemm_8ph(
    const unsigned short* __restrict__ A,
    const unsigned short* __restrict__ Bt,
    const float* __restrict__ bias_base,     // [8][2][N]
    const int* __restrict__ op_ptr, int expert,
    OUT_T* __restrict__ Cout, int M, int N, int K, int nbn)
{
  constexpr int BM = 256, BK = 64;
  constexpr int BN = FN * 64;
  constexpr int WN = FN * 16;
  constexpr int S  = 4 + FN;              // stage instrs per K-tile
  constexpr int BUF = (BM + BN) * BK;     // shorts per double-buffer half
  __shared__ short smem[2 * BUF];

  const int tid  = threadIdx.x;
  const int wid  = tid >> 6, lane = tid & 63;
  const int wm   = wid >> 2, wn = wid & 3;       // wave grid 2M x 4N
  const int lq   = lane >> 4, lr = lane & 15;

  // XCD-aware bijective swizzle (nwg % 8 == 0), bm-major within an XCD chunk
  const int nwg = gridDim.x;
  const int id  = blockIdx.x;
  const int s   = (id & 7) * (nwg >> 3) + (id >> 3);
  const int bm  = s / nbn, bn = s % nbn;

  const unsigned short* Ab = A  + (size_t)bm * BM * K;
  const unsigned short* Bb = Bt + (size_t)bn * BN * K;

  f32x4 acc[8][FN] = {};

  // prologue: stage all of K-tile 0 into buffer 0
#pragma unroll
  for (int j = 0; j < S; j += 2) stage_pair<FN>(j, Ab, Bb, K, 0, smem, tid);

  const int nkt = K / BK;
  for (int t = 0; t < nkt; ++t) {
    short* cur = smem + (t & 1) * BUF;
    short* nxt = smem + ((t + 1) & 1) * BUF;
    const int kb = (t + 1) * BK;
    const bool pf = (t + 1) < nkt;

    // tile boundary: issue 2 prefetch loads, then counted wait (T4)
    if (pf) { stage_pair<FN>(0, Ab, Bb, K, kb, nxt, tid); VMCNT2; }
    else    { VMCNT0; }
    SBAR; SCHEDB;

    const char* cA = (const char*)cur;
    const char* cB = (const char*)(cur + BM * BK);
    short8 bf[FN];
#pragma unroll
    for (int ks = 0; ks < 2; ++ks) {
      const int ch = ((ks << 2) | lq) ^ (lr & 7);   // swizzled k-chunk
#pragma unroll
      for (int mh = 0; mh < 2; ++mh) {
        // --- phase (ks, mh): ds_read cluster ---
        short8 af[4];
#pragma unroll
        for (int mm = 0; mm < 4; ++mm) {
          const int ra = wm * 128 + mh * 64 + mm * 16 + lr;
          af[mm] = *(const short8*)(cA + ra * 128 + ch * 16);
        }
        if (mh == 0) {
#pragma unroll
          for (int n = 0; n < FN; ++n) {
            const int rb = wn * WN + n * 16 + lr;
            bf[n] = *(const short8*)(cB + rb * 128 + ch * 16);
          }
        }
        // --- issue this phase's prefetch pair (into idle buffer) ---
        const int ph = ks * 2 + mh;
        if (pf && (ph * 2 + 4) <= S) stage_pair<FN>(ph * 2 + 2, Ab, Bb, K, kb, nxt, tid);
        // --- MFMA cluster ---
        LGKM0; SCHEDB;
        __builtin_amdgcn_s_setprio(1);
#pragma unroll
        for (int mm = 0; mm < 4; ++mm)
#pragma unroll
          for (int n = 0; n < FN; ++n)
            acc[mh * 4 + mm][n] = __builtin_amdgcn_mfma_f32_16x16x32_bf16(
                af[mm], bf[n], acc[mh * 4 + mm][n], 0, 0, 0);
        __builtin_amdgcn_s_setprio(0);
        SCHEDB; SBAR;
      }
    }
  }

  // Epilogue: C/D layout col=lane&15, row=(lane>>4)*4+reg [m89-verified]
  const int op = *op_ptr;
  const float* bias = bias_base + ((size_t)op * 2 + (size_t)expert) * (size_t)N;
#pragma unroll
  for (int f = 0; f < 8; ++f) {
    const int grow0 = bm * BM + wm * 128 + f * 16 + lq * 4;
#pragma unroll
    for (int n = 0; n < FN; ++n) {
      const int gcol = bn * BN + wn * WN + n * 16 + lr;
      const float bv = bias[gcol];
#pragma unroll
      for (int r = 0; r < 4; ++r) {
        float v = acc[f][n][r] + bv;
        if constexpr (GELU) v = gelu_tanh(v);
        const size_t off = (size_t)(grow0 + r) * N + gcol;
        if constexpr (std::is_same<OUT_T, float>::value) Cout[off] = v;
        else Cout[off] = f2bf(v);
      }
    }
  }
}

// --------------------------- launcher ---------------------------------------
extern "C" void kernel_launch(void* const* d_in, const int* in_sizes, int n_in,
                              void* d_out, int out_size, void* d_ws, size_t ws_size,
                              hipStream_t stream) {
  const float* x  = (const float*)d_in[0];
  const float* W1 = (const float*)d_in[1];   // [8][2][1024][4096]
  const float* b1 = (const float*)d_in[2];   // [8][2][4096]
  const float* W2 = (const float*)d_in[3];   // [8][2][4096][1024]
  const float* b2 = (const float*)d_in[4];   // [8][2][1024]
  float* out = (float*)d_out;

  const int D = 1024, F = 4096, M = 8192;    // M = B*S = 4*2048

  // ws layout: [op int, pad 1KB][xb 16.8MB][w1t 16.8MB][w2t 16.8MB][h 67.1MB]
  char* ws = (char*)d_ws;
  int* op_ptr = (int*)ws;
  unsigned short* xb  = (unsigned short*)(ws + 1024);
  unsigned short* w1t = (unsigned short*)(ws + 1024 + (size_t)M * D * 2);
  unsigned short* w2t = (unsigned short*)(ws + 1024 + (size_t)M * D * 2 + (size_t)2 * D * F * 2);
  unsigned short* h   = (unsigned short*)(ws + 1024 + (size_t)M * D * 2 + (size_t)4 * D * F * 2);
  unsigned short* x1b = (unsigned short*)d_out;  // stage-0 output parked in d_out

  route_kernel<<<1, 64, 0, stream>>>(x, op_ptr);
  cvt_x_kernel<<<(M * D / 4 + 255) / 256, 256, 0, stream>>>(x, xb, M * D / 4);

  for (int e = 0; e < 2; ++e) {
    // W1[op,e]: [D][F] -> w1t[e]: [F][D]
    transpose_cvt_kernel<<<dim3(F / 64, D / 64), 256, 0, stream>>>(W1, w1t + (size_t)e * F * D, op_ptr, D, F, e);
    // W2[op,e]: [F][D] -> w2t[e]: [D][F]
    transpose_cvt_kernel<<<dim3(D / 64, F / 64), 256, 0, stream>>>(W2, w2t + (size_t)e * D * F, op_ptr, F, D, e);
  }

  // GEMM1: M=8192, N=4096, K=1024 -> BM=256, BN=256, grid 32*16=512
  // GEMM2: M=8192, N=1024, K=4096 -> BM=256, BN=128, grid 32*8 =256
  // expert 0
  gemm_8ph<4, true,  unsigned short><<<(M/256)*(F/256), 512, 0, stream>>>(xb,  w1t,                 b1, op_ptr, 0, h,   M, F, D, F/256);
  gemm_8ph<2, false, unsigned short><<<(M/256)*(D/128), 512, 0, stream>>>(h,   w2t,                 b2, op_ptr, 0, x1b, M, D, F, D/128);
  // expert 1
  gemm_8ph<4, true,  unsigned short><<<(M/256)*(F/256), 512, 0, stream>>>(x1b, w1t + (size_t)F * D, b1, op_ptr, 1, h,   M, F, D, F/256);
  gemm_8ph<2, false, float         ><<<(M/256)*(D/128), 512, 0, stream>>>(h,   w2t + (size_t)D * F, b2, op_ptr, 1, out, M, D, F, D/128);
}